// Round 6
// baseline (83.880 us; speedup 1.0000x reference)
//
#include <hip/hip_runtime.h>
#include <hip/hip_bf16.h>

// V[k,d] = sum_n a_bar[k,n]*x[d,n] - c[k,d]*sum_n a_bar[k,n]
// K=64, D=512, N=131072.
// Stage 1: reg-staged bf16-LDS split-N MFMA GEMM, BK=64, 24KB buffers x2,
//          3 blocks/CU, T14 issue-early/write-late -> bf16 partials in d_ws.
// Stage 2: reduce partials + fused c*a_sum epilogue.

#define K_ROWS 64
#define D_COLS 512
#define N_RED  131072LL
#define TOTAL_STEPS 2048          // N / 64
#define XBY 16384                 // bf16 x-tile: 128 rows x 64 n x 2B
#define ABY 8192                  // bf16 a-tile:  64 rows x 64 n x 2B
#define BUFB (XBY + ABY)          // 24 KB

typedef __attribute__((ext_vector_type(8))) short short8;
typedef __attribute__((ext_vector_type(4))) float f32x4;

static __device__ __forceinline__ short f2bf(float f) {
    __bf16 h = (__bf16)f;                  // RNE; pairs fuse to v_cvt_pk_bf16_f32
    return __builtin_bit_cast(short, h);
}
static __device__ __forceinline__ float bf2f(unsigned short u) {
    return __builtin_bit_cast(float, (unsigned)u << 16);
}
static __device__ __forceinline__ short8 cvt8(float4 a, float4 b) {
    short8 r;
    r[0] = f2bf(a.x); r[1] = f2bf(a.y); r[2] = f2bf(a.z); r[3] = f2bf(a.w);
    r[4] = f2bf(b.x); r[5] = f2bf(b.y); r[6] = f2bf(b.z); r[7] = f2bf(b.w);
    return r;
}

// Grid: 4*S blocks of 512 threads (8 waves), 48KB LDS, 3 blocks/CU.
// bid = m*32 + g*8 + x7: col-group g (d-cols [g*128,+128)), n-chunk
// s = m*8 + x7 — the 4 g's of one s share x7 => same XCD (a_bar L2-shared).
// Uneven step split: block s covers steps [s*2048/S, (s+1)*2048/S).
// LDS tiles bf16, row = 128B = 8 x 16B units, unit ^= row&7 (2-way max on
// both ds_write_b128 and frag ds_read_b128 -> free).
// Per K-step (64 n): barrier -> issue 6 dwordx4 (T14) -> 10 ds_read_b128 +
// 8 MFMA -> vmcnt-wait + cvt + 3 ds_write_b128 into the other buffer.
__global__ __launch_bounds__(512, 6) void vlad_stage1(
    const float* __restrict__ x, const float* __restrict__ ab,
    unsigned short* __restrict__ pax, float* __restrict__ pasum, int S)
{
    __shared__ __align__(16) char smem[2][BUFB];

    const int bid = blockIdx.x;
    const int x7  = bid & 7;
    const int g   = (bid >> 3) & 3;
    const int m   = bid >> 5;
    const int s   = m * 8 + x7;
    const int tid = threadIdx.x;
    const int w   = tid >> 6, l = tid & 63, lr = l & 15, lg = l >> 4;
    const int d0  = g * 128;

    const int st0 = (int)(((long long)s       * TOTAL_STEPS) / S);
    const int st1 = (int)(((long long)(s + 1) * TOTAL_STEPS) / S);

    // ---- staging geometry ----
    // x: thread -> row tid>>2, 16 consecutive f32 n at (tid&3)*16 (2 bf16 units)
    const int xrow = tid >> 2, xq = tid & 3;
    const float* gx = x + (size_t)(d0 + xrow) * N_RED + xq * 16;
    const int xo0 = xrow * 128 + (((xq * 2)     ^ (xrow & 7)) << 4);
    const int xo1 = xrow * 128 + (((xq * 2 + 1) ^ (xrow & 7)) << 4);
    // a: thread -> row tid>>3, 8 consecutive f32 n at (tid&7)*8 (1 bf16 unit)
    const int arow = tid >> 3, aq = tid & 7;
    const float* ga = ab + (size_t)arow * N_RED + aq * 8;
    const int ao0 = XBY + arow * 128 + ((aq ^ (arow & 7)) << 4);

    // ---- fragment read offsets (single base + imm offsets after codegen) ----
    const int swz = lr & 7;
    int fx[2], fa[4][2];
    #pragma unroll
    for (int kk = 0; kk < 2; ++kk) {
        fx[kk] = (w * 16 + lr) * 128 + ((((kk << 2) | lg) ^ swz) << 4);
        #pragma unroll
        for (int t = 0; t < 4; ++t)
            fa[t][kk] = XBY + (t * 16 + lr) * 128 + ((((kk << 2) | lg) ^ swz) << 4);
    }

    f32x4 acc[4] = {};
    float asum = 0.f;
    float4 X0, X1, X2, X3, A0, A1;

    auto issue = [&](int it) {
        const float* p = gx + (size_t)it * 64;
        X0 = *(const float4*)(p);
        X1 = *(const float4*)(p + 4);
        X2 = *(const float4*)(p + 8);
        X3 = *(const float4*)(p + 12);
        const float* q = ga + (size_t)it * 64;
        A0 = *(const float4*)(q);
        A1 = *(const float4*)(q + 4);
    };
    auto commit = [&](char* buf) {
        *(short8*)(buf + xo0) = cvt8(X0, X1);
        *(short8*)(buf + xo1) = cvt8(X2, X3);
        *(short8*)(buf + ao0) = cvt8(A0, A1);
        asum += ((A0.x + A0.y) + (A0.z + A0.w))
              + ((A1.x + A1.y) + (A1.z + A1.w));
    };

    issue(st0);
    commit(smem[0]);

    int cur = 0;
    #pragma unroll 1
    for (int it = st0; it < st1; ++it) {
        const bool more = (it + 1 < st1);
        __syncthreads();              // buf[cur] writes drained; buf[cur^1] free
        if (more) issue(it + 1);      // loads fly under the compute phase (T14)

        const char* b = smem[cur];
        #pragma unroll
        for (int kk = 0; kk < 2; ++kk) {
            short8 xf  = *(const short8*)(b + fx[kk]);
            short8 a0f = *(const short8*)(b + fa[0][kk]);
            short8 a1f = *(const short8*)(b + fa[1][kk]);
            short8 a2f = *(const short8*)(b + fa[2][kk]);
            short8 a3f = *(const short8*)(b + fa[3][kk]);
            acc[0] = __builtin_amdgcn_mfma_f32_16x16x32_bf16(a0f, xf, acc[0], 0, 0, 0);
            acc[1] = __builtin_amdgcn_mfma_f32_16x16x32_bf16(a1f, xf, acc[1], 0, 0, 0);
            acc[2] = __builtin_amdgcn_mfma_f32_16x16x32_bf16(a2f, xf, acc[2], 0, 0, 0);
            acc[3] = __builtin_amdgcn_mfma_f32_16x16x32_bf16(a3f, xf, acc[3], 0, 0, 0);
        }

        if (more) commit(smem[cur ^ 1]);   // cvt waits vmcnt; write-late
        cur ^= 1;
    }

    // bf16 partials, fragment-layout: f = (((g*8+w)*4+t)*4+r)*64 + l
    // (k = t*16+lg*4+r, d = g*128+w*16+lr) — coalesced 128B lines.
    unsigned short* dst = pax + (size_t)s * (K_ROWS * D_COLS);
    #pragma unroll
    for (int t = 0; t < 4; ++t)
        #pragma unroll
        for (int r = 0; r < 4; ++r)
            dst[(((g * 8 + w) * 4 + t) * 4 + r) * 64 + l] =
                (unsigned short)f2bf(acc[t][r]);

    // a_sum partial: reduce the 8 staging threads of each a-row (adjacent lanes)
    if (g == 0) {
        asum += __shfl_xor(asum, 1, 64);
        asum += __shfl_xor(asum, 2, 64);
        asum += __shfl_xor(asum, 4, 64);
        if ((tid & 7) == 0) pasum[s * K_ROWS + arow] = asum;
    }
}

// Grid: 32768/64 = 512 blocks of 256. Block covers 64 consecutive fragment
// indices (fixed g,w,t,r; lg,lr vary): 4-way s-split + LDS combine,
// block-parallel a_sum reduce over the block's 4 k-rows.
__global__ __launch_bounds__(256) void vlad_stage2(
    const unsigned short* __restrict__ pax, const float* __restrict__ pasum,
    const float* __restrict__ c, float* __restrict__ out, int S)
{
    __shared__ float red[256];
    __shared__ float ared[256];
    const int t  = threadIdx.x;
    const int fo = t & 63;
    const int sp = t >> 6;
    const int fb = blockIdx.x * 64;
    const int f  = fb + fo;

    float acc = 0.f;
    for (int s = sp; s < S; s += 4)
        acc += bf2f(pax[(size_t)s * (K_ROWS * D_COLS) + f]);
    red[t] = acc;

    // a_sum partials for this block's 4 k-rows (indexed by lg = t&3)
    const int R = (fb >> 6) & 3, T = (fb >> 8) & 3;
    const int ka = T * 16 + (t & 3) * 4 + R;
    float pa = 0.f;
    for (int s2 = t >> 2; s2 < S; s2 += 64)
        pa += pasum[s2 * K_ROWS + ka];
    ared[t] = pa;
    __syncthreads();

    for (int st = 128; st >= 4; st >>= 1) {
        if (t < st) ared[t] += ared[t + st];
        __syncthreads();
    }
    if (sp == 0) {
        const int lr = f & 15, lg = (f >> 4) & 3;
        const int r  = (f >> 6) & 3, tt = (f >> 8) & 3;
        const int w  = (f >> 10) & 7, gg = (f >> 13) & 3;
        const int k  = tt * 16 + lg * 4 + r;
        const int d  = gg * 128 + w * 16 + lr;
        float v = red[t] + red[t + 64] + red[t + 128] + red[t + 192];
        out[k * D_COLS + d] = v - c[k * D_COLS + d] * ared[lg];
    }
}

extern "C" void kernel_launch(void* const* d_in, const int* in_sizes, int n_in,
                              void* d_out, int out_size, void* d_ws, size_t ws_size,
                              hipStream_t stream)
{
    const float* x  = (const float*)d_in[0];
    const float* ab = (const float*)d_in[1];
    const float* c  = (const float*)d_in[2];
    float* out = (float*)d_out;

    // S=192 -> grid 768 = exactly 3 blocks/CU; halve if ws too small
    // (S must stay a multiple of 8 for the XCD mapping).
    int S = 192;
    while (S > 24 &&
           (size_t)S * ((size_t)K_ROWS * D_COLS * 2 + K_ROWS * 4) > ws_size)
        S >>= 1;

    unsigned short* pax = (unsigned short*)d_ws;
    float* pasum = (float*)((char*)d_ws + (size_t)S * K_ROWS * D_COLS * 2);

    vlad_stage1<<<dim3(4 * S), dim3(512), 0, stream>>>(x, ab, pax, pasum, S);
    vlad_stage2<<<dim3((K_ROWS * D_COLS) / 64), dim3(256), 0, stream>>>(pax, pasum, c, out, S);
}

// Round 7
// 74.031 us; speedup vs baseline: 1.1330x; 1.1330x over previous
//
#include <hip/hip_runtime.h>
#include <hip/hip_bf16.h>

// V[k,d] = sum_n a_bar[k,n]*x[d,n] - c[k,d]*sum_n a_bar[k,n]
// K=64, D=512, N=131072.
// Stage 1: split-N MFMA GEMM. x-fragments loaded DIRECTLY from global into
//          MFMA B-operand registers (1 iter in flight); a_bar staged in LDS
//          bf16, 3 buffers, 2 iters in flight (counted vmcnt falls out of
//          dataflow). bf16 partials (fragment layout) -> d_ws.
// Stage 2: reduce partials + fused c*a_sum epilogue.

#define K_ROWS 64
#define D_COLS 512
#define N_RED  131072LL
#define TOTAL_STEPS 4096          // N / 32 (BK = 32)
#define ABUF 4096                 // bf16 a-tile: 64 rows x 32 n x 2B

typedef __attribute__((ext_vector_type(8))) short short8;
typedef __attribute__((ext_vector_type(4))) float f32x4;

static __device__ __forceinline__ short f2bf(float f) {
    __bf16 h = (__bf16)f;                  // RNE; pairs fuse to v_cvt_pk_bf16_f32
    return __builtin_bit_cast(short, h);
}
static __device__ __forceinline__ float bf2f(unsigned short u) {
    return __builtin_bit_cast(float, (unsigned)u << 16);
}
static __device__ __forceinline__ short8 cvt8(float4 a, float4 b) {
    short8 r;
    r[0] = f2bf(a.x); r[1] = f2bf(a.y); r[2] = f2bf(a.z); r[3] = f2bf(a.w);
    r[4] = f2bf(b.x); r[5] = f2bf(b.y); r[6] = f2bf(b.z); r[7] = f2bf(b.w);
    return r;
}

// Grid: 4*S blocks of 512 threads (8 waves), 12KB LDS, 3 blocks/CU (VGPR cap).
// bid = m*32 + g*8 + x7: col-group g (d-cols [g*128,+128)), n-chunk s = m*8+x7
// — the 4 g's of one s share x7 => same XCD (a_bar window L2-shared).
// Uneven step split: block s covers steps [s*4096/S, (s+1)*4096/S).
//
// Per iter it:  barrier
//   issue a(it+2) -> B regs          (tid<256; 2 dwordx4)
//   xf = cvt(X); issue x(it+1) -> X  (2 dwordx4, direct B-fragment)
//   4x ds_read_b128 a-frags + 4 MFMA
//   commit a(it+1): cvt A -> ds_write_b128 buf[(it+1)%3]; A <- B
// No vmcnt ever drains to 0 in the loop (4 newer loads outstanding at each
// wait); x and a both get a full-iteration latency window.
__global__ __launch_bounds__(512, 6) void vlad_stage1(
    const float* __restrict__ x, const float* __restrict__ ab,
    unsigned short* __restrict__ pax, float* __restrict__ pasum, int S)
{
    __shared__ __align__(16) char smem[3][ABUF];

    const int bid = blockIdx.x;
    const int x7  = bid & 7;
    const int g   = (bid >> 3) & 3;
    const int m   = bid >> 5;
    const int s   = m * 8 + x7;
    const int tid = threadIdx.x;
    const int w   = tid >> 6, l = tid & 63, lr = l & 15, lg = l >> 4;
    const int d0  = g * 128;

    const int st0 = (int)(((long long)s       * TOTAL_STEPS) / S);
    const int st1 = (int)(((long long)(s + 1) * TOTAL_STEPS) / S);

    // x: direct B-fragment pointer — lane holds rows d0+w*16+lr, 8 n at lg*8.
    const float* gx = x + (size_t)(d0 + w * 16 + lr) * N_RED + lg * 8;

    // a staging: threads 0-255, row tid>>2, 8 n at (tid&3)*8.
    const bool at  = (tid < 256);
    const int arow = tid >> 2, aq = tid & 3;
    const float* ga = ab + (size_t)arow * N_RED + aq * 8;
    const int awoff = arow * 64 + ((aq ^ (arow & 3)) << 4);   // XOR-swizzled unit

    // a fragment read offsets (row = t*16+lr, unit lg; row&3 == lr&3).
    const int swz = lr & 3;
    int fa[4];
    #pragma unroll
    for (int t = 0; t < 4; ++t)
        fa[t] = (t * 16 + lr) * 64 + ((lg ^ swz) << 4);

    f32x4 acc[4] = {};
    float asum = 0.f;
    float4 X0, X1, A0, A1, B0, B1;

    // ---- prologue ----
    if (at) { const float* q = ga + (size_t)st0 * 32; A0 = *(const float4*)q; A1 = *(const float4*)(q + 4); }
    { const float* p = gx + (size_t)st0 * 32; X0 = *(const float4*)p; X1 = *(const float4*)(p + 4); }
    if (at) {
        *(short8*)(smem[0] + awoff) = cvt8(A0, A1);   // one-time vmcnt stall
        asum += ((A0.x + A0.y) + (A0.z + A0.w)) + ((A1.x + A1.y) + (A1.z + A1.w));
    }
    if (at && st0 + 1 < st1) { const float* q = ga + (size_t)(st0 + 1) * 32; A0 = *(const float4*)q; A1 = *(const float4*)(q + 4); }

    int rb = 0;
    #pragma unroll 1
    for (int it = st0; it < st1; ++it) {
        __syncthreads();                       // buf[rb] ready; frees buf[rb+1] writers
        if (at && it + 2 < st1) {              // issue a(it+2)
            const float* q = ga + (size_t)(it + 2) * 32;
            B0 = *(const float4*)q; B1 = *(const float4*)(q + 4);
        }
        short8 xf = cvt8(X0, X1);              // consume x(it)
        if (it + 1 < st1) {                    // issue x(it+1) in place
            const float* p = gx + (size_t)(it + 1) * 32;
            X0 = *(const float4*)p; X1 = *(const float4*)(p + 4);
        }

        const char* b = smem[rb];
        short8 a0f = *(const short8*)(b + fa[0]);
        short8 a1f = *(const short8*)(b + fa[1]);
        short8 a2f = *(const short8*)(b + fa[2]);
        short8 a3f = *(const short8*)(b + fa[3]);
        acc[0] = __builtin_amdgcn_mfma_f32_16x16x32_bf16(a0f, xf, acc[0], 0, 0, 0);
        acc[1] = __builtin_amdgcn_mfma_f32_16x16x32_bf16(a1f, xf, acc[1], 0, 0, 0);
        acc[2] = __builtin_amdgcn_mfma_f32_16x16x32_bf16(a2f, xf, acc[2], 0, 0, 0);
        acc[3] = __builtin_amdgcn_mfma_f32_16x16x32_bf16(a3f, xf, acc[3], 0, 0, 0);

        if (at && it + 1 < st1) {              // commit a(it+1); window = 1 iter
            int wb_ = (rb + 1 == 3) ? 0 : rb + 1;
            *(short8*)(smem[wb_] + awoff) = cvt8(A0, A1);
            asum += ((A0.x + A0.y) + (A0.z + A0.w)) + ((A1.x + A1.y) + (A1.z + A1.w));
            A0 = B0; A1 = B1;
        }
        rb = (rb + 1 == 3) ? 0 : rb + 1;
    }

    // bf16 partials, fragment-layout: f = (((g*8+w)*4+t)*4+r)*64 + l
    // (k = t*16+lg*4+r, d = g*128+w*16+lr) — coalesced 128B lines.
    unsigned short* dst = pax + (size_t)s * (K_ROWS * D_COLS);
    #pragma unroll
    for (int t = 0; t < 4; ++t)
        #pragma unroll
        for (int r = 0; r < 4; ++r)
            dst[(((g * 8 + w) * 4 + t) * 4 + r) * 64 + l] =
                (unsigned short)f2bf(acc[t][r]);

    // a_sum partial: 4 stagers per a-row (adjacent lanes aq=0..3).
    if (g == 0 && at) {
        asum += __shfl_xor(asum, 1, 64);
        asum += __shfl_xor(asum, 2, 64);
        if (aq == 0) pasum[s * K_ROWS + arow] = asum;
    }
}

// Grid: 32768/64 = 512 blocks of 256. Block covers 64 consecutive fragment
// indices (fixed g,w,t,r; lg,lr vary): 4-way s-split + LDS combine,
// block-parallel a_sum reduce over the block's 4 k-rows.
__global__ __launch_bounds__(256) void vlad_stage2(
    const unsigned short* __restrict__ pax, const float* __restrict__ pasum,
    const float* __restrict__ c, float* __restrict__ out, int S)
{
    __shared__ float red[256];
    __shared__ float ared[256];
    const int t  = threadIdx.x;
    const int fo = t & 63;
    const int sp = t >> 6;
    const int fb = blockIdx.x * 64;
    const int f  = fb + fo;

    float acc = 0.f;
    for (int s = sp; s < S; s += 4)
        acc += bf2f(pax[(size_t)s * (K_ROWS * D_COLS) + f]);
    red[t] = acc;

    // a_sum partials for this block's 4 k-rows (indexed by lg = t&3)
    const int R = (fb >> 6) & 3, T = (fb >> 8) & 3;
    const int ka = T * 16 + (t & 3) * 4 + R;
    float pa = 0.f;
    for (int s2 = t >> 2; s2 < S; s2 += 64)
        pa += pasum[s2 * K_ROWS + ka];
    ared[t] = pa;
    __syncthreads();

    for (int st = 128; st >= 4; st >>= 1) {
        if (t < st) ared[t] += ared[t + st];
        __syncthreads();
    }
    if (sp == 0) {
        const int lr = f & 15, lg = (f >> 4) & 3;
        const int r  = (f >> 6) & 3, tt = (f >> 8) & 3;
        const int w  = (f >> 10) & 7, gg = (f >> 13) & 3;
        const int k  = tt * 16 + lg * 4 + r;
        const int d  = gg * 128 + w * 16 + lr;
        float v = red[t] + red[t + 64] + red[t + 128] + red[t + 192];
        out[k * D_COLS + d] = v - c[k * D_COLS + d] * ared[lg];
    }
}

extern "C" void kernel_launch(void* const* d_in, const int* in_sizes, int n_in,
                              void* d_out, int out_size, void* d_ws, size_t ws_size,
                              hipStream_t stream)
{
    const float* x  = (const float*)d_in[0];
    const float* ab = (const float*)d_in[1];
    const float* c  = (const float*)d_in[2];
    float* out = (float*)d_out;

    // S=192 -> grid 768 = exactly 3 blocks/CU; halve if ws too small
    // (S must stay a multiple of 8 for the XCD mapping).
    int S = 192;
    while (S > 24 &&
           (size_t)S * ((size_t)K_ROWS * D_COLS * 2 + K_ROWS * 4) > ws_size)
        S >>= 1;

    unsigned short* pax = (unsigned short*)d_ws;
    float* pasum = (float*)((char*)d_ws + (size_t)S * K_ROWS * D_COLS * 2);

    vlad_stage1<<<dim3(4 * S), dim3(512), 0, stream>>>(x, ab, pax, pasum, S);
    vlad_stage2<<<dim3((K_ROWS * D_COLS) / 64), dim3(256), 0, stream>>>(pax, pasum, c, out, S);
}